// Round 5
// baseline (6890.751 us; speedup 1.0000x reference)
//
#include <hip/hip_runtime.h>

#define Bn 128
#define Wn 64

typedef _Float16 h2 __attribute__((ext_vector_type(2)));

// ---- inter-WG exchange state (flags reset every launch) ----
__device__ unsigned g_f1[512];               // score-partial ready, value = t+1
__device__ unsigned g_f2[512];               // state-quarter ready, value = t+1
__device__ unsigned g_att[512][64];          // score partials (f32 bits)
__device__ unsigned g_state[512][64];        // h pairs [0..32), c pairs [32..64)
__device__ unsigned g_ep16[Bn * Wn * 128];   // eproj f16 pairs [b][w][128]
__device__ float4 g_encfc[Bn * Wn];          // fc_w[:, :256] @ enc  per (b,w)
__device__ float4 g_encfcf[Bn * Wn];         // fcf_w[:, 256:] @ enc per (b,w)

__device__ __forceinline__ float ftanh(float x) {
  float p = __builtin_exp2f(x * 2.885390081777927f);
  return 1.0f - 2.0f * __builtin_amdgcn_rcpf(p + 1.0f);
}
__device__ __forceinline__ float fsigm(float x) {
  float p = __builtin_exp2f(-x * 1.4426950408889634f);
  return __builtin_amdgcn_rcpf(1.0f + p);
}
__device__ __forceinline__ float dot4(float4 a, float4 b) {
  return a.x * b.x + a.y * b.y + a.z * b.z + a.w * b.w;
}
__device__ __forceinline__ float fd2(unsigned w, unsigned h, float acc) {
  h2 a = __builtin_bit_cast(h2, w), b = __builtin_bit_cast(h2, h);
#if __has_builtin(__builtin_amdgcn_fdot2)
  return __builtin_amdgcn_fdot2(a, b, acc, false);
#else
  return acc + (float)a.x * (float)b.x + (float)a.y * (float)b.y;
#endif
}
__device__ __forceinline__ float fd2x4u(uint4 w, uint4 h, float acc) {
  acc = fd2(w.x, h.x, acc);
  acc = fd2(w.y, h.y, acc);
  acc = fd2(w.z, h.z, acc);
  acc = fd2(w.w, h.w, acc);
  return acc;
}
__device__ __forceinline__ unsigned pk(float a, float b) {
  h2 h = {(_Float16)a, (_Float16)b};
  return __builtin_bit_cast(unsigned, h);
}
__device__ __forceinline__ void ast(unsigned* p, unsigned v) {
  __hip_atomic_store(p, v, __ATOMIC_RELAXED, __HIP_MEMORY_SCOPE_AGENT);
}
__device__ __forceinline__ void ast_rel(unsigned* p, unsigned v) {
  __hip_atomic_store(p, v, __ATOMIC_RELEASE, __HIP_MEMORY_SCOPE_AGENT);
}
__device__ __forceinline__ unsigned ald(unsigned* p) {
  return __hip_atomic_load(p, __ATOMIC_RELAXED, __HIP_MEMORY_SCOPE_AGENT);
}
__device__ __forceinline__ unsigned ald_acq(unsigned* p) {
  return __hip_atomic_load(p, __ATOMIC_ACQUIRE, __HIP_MEMORY_SCOPE_AGENT);
}

// ---------------- reset: flags + out (atomicAdd target) ----------------
__global__ void reset_kernel(float* out) {
  int t = threadIdx.x;
  if (t < 512) { g_f1[t] = 0u; g_f2[t] = 0u; out[t] = 0.f; }
}

// ---------------- eproj: b1 + W1e @ enc -> f16 pairs ----------------
__global__ __launch_bounds__(256) void eproj_kernel(const float* __restrict__ enc,
                                                    const float* __restrict__ w1,
                                                    const float* __restrict__ b1) {
  __shared__ __align__(16) float4 encs[16][64];
  __shared__ float accs[16][256];
  const int m0 = blockIdx.x * 16;
  const int tid = threadIdx.x;
  const float4* eg = (const float4*)(enc + (size_t)m0 * 256);
#pragma unroll
  for (int i = 0; i < 4; i++) {
    int idx = tid + 256 * i;
    encs[idx >> 6][idx & 63] = eg[idx];
  }
  __syncthreads();
  const int e = tid;
  float acc[16];
#pragma unroll
  for (int i = 0; i < 16; i++) acc[i] = 0.f;
  const float4* wrow = (const float4*)(w1 + e * 768 + 512);
  for (int k4 = 0; k4 < 64; k4++) {
    float4 wv = wrow[k4];
#pragma unroll
    for (int i = 0; i < 16; i++) acc[i] += dot4(wv, encs[i][k4]);
  }
  float bb = b1[e];
#pragma unroll
  for (int i = 0; i < 16; i++) accs[i][e] = acc[i] + bb;
  __syncthreads();
#pragma unroll
  for (int r = 0; r < 8; r++) {
    int idx = r * 256 + tid;  // 0..2047
    int i = idx >> 7, jp = idx & 127;
    g_ep16[(size_t)(m0 + i) * 128 + jp] = pk(accs[i][2 * jp], accs[i][2 * jp + 1]);
  }
}

// ---------------- ENCFC / ENCFCF precompute ----------------
__global__ __launch_bounds__(256) void encfc_kernel(const float* __restrict__ enc,
                                                    const float* __restrict__ fc_w,
                                                    const float* __restrict__ fcf_w) {
  __shared__ __align__(16) float4 encs[16][64];
  const int m0 = blockIdx.x * 16;
  const int tid = threadIdx.x;
  const float4* eg = (const float4*)(enc + (size_t)m0 * 256);
#pragma unroll
  for (int i = 0; i < 4; i++) {
    int idx = tid + 256 * i;
    encs[idx >> 6][idx & 63] = eg[idx];
  }
  __syncthreads();
  if (tid < 128) {
    const int r = tid >> 3, o = tid & 7;
    const float* wr = (o < 4) ? (fc_w + o * 260) : (fcf_w + (o - 4) * 512 + 256);
    const float4* w4 = (const float4*)wr;
    float a = 0.f;
#pragma unroll 8
    for (int k = 0; k < 64; k++) a += dot4(w4[k], encs[r][k]);
    if (o < 4) ((float*)&g_encfc[m0 + r])[o] = a;
    else ((float*)&g_encfcf[m0 + r])[o - 4] = a;
  }
}

// ---------------- decoder: 4 WGs per chain; weights truly register-resident ----------------
// per WG: w1 e-quarter (64 VGPR/thr) + w_hh d-quarter (128 VGPR/thr, 1 gate-row/thr)
__global__ __launch_bounds__(256, 2) void decoder_kernel(
    const float* __restrict__ w1, const float* __restrict__ w_hh,
    const float* __restrict__ yhist, const float* __restrict__ w2,
    const float* __restrict__ w_ih, const float* __restrict__ b_ih,
    const float* __restrict__ b_hh,
    const float* __restrict__ fc_w, const float* __restrict__ fc_b,
    const float* __restrict__ fcf_w, const float* __restrict__ fcf_b,
    float* __restrict__ out) {
  __shared__ unsigned st_l[256];     // full state pairs: h [0..128), c [128..256)
  __shared__ float hcp_l[64];        // own e-quarter hcp
  __shared__ float att_l[64];
  __shared__ float ag_l[256];        // gates [q][d_local]
  __shared__ float c_l[64];          // own-quarter c (f32)
  __shared__ float hn_l[64];         // own-quarter h (f32)
  __shared__ float w2_l[64];
  __shared__ unsigned ep_l[64 * 33]; // eproj own e-quarter, stride 33 (bank-friendly)
  __shared__ __align__(16) float4 yh_l[64];
  __shared__ float fcy_l[16];
  __shared__ float fcb_l[4];

  const int g = blockIdx.x, tid = threadIdx.x;
  const int b = g & 127, p = g >> 7;   // p in 0..3
  const int l = tid & 63, q = tid >> 6;

  // P1 mapping: 4 threads per e-row, each a 128-k quarter of the 512-k row
  const int row = tid >> 2, kq = tid & 3;
  // which 32-pair half of this thread's quarter is this WG's own state
  int ownHalf = -1;
  if (kq == (p >> 1) || kq == 2 + (p >> 1)) ownHalf = p & 1;

  // ---- register-resident weights ----
  uint4 w1r[16];  // pairs [64*kq .. +64) of w1 row (64p+row), cols 0..511 = [W1h|W1c]
  {
    const float4* s = (const float4*)(w1 + (size_t)(64 * p + row) * 768 + kq * 128);
#pragma unroll
    for (int i = 0; i < 16; i++) {
      float4 x = s[2 * i], y = s[2 * i + 1];
      w1r[i].x = pk(x.x, x.y); w1r[i].y = pk(x.z, x.w);
      w1r[i].z = pk(y.x, y.y); w1r[i].w = pk(y.z, y.w);
    }
  }
  const int grow = q * 256 + 64 * p + l;  // gate row: wave q = gate (i,f,g,o)
  uint4 whr[32];                          // full 256-f16 w_hh row
  {
    const float4* s = (const float4*)(w_hh + (size_t)grow * 256);
#pragma unroll
    for (int i = 0; i < 32; i++) {
      float4 x = s[2 * i], y = s[2 * i + 1];
      whr[i].x = pk(x.x, x.y); whr[i].y = pk(x.z, x.w);
      whr[i].z = pk(y.x, y.y); whr[i].w = pk(y.z, y.w);
    }
  }
  const float4 wih = *(const float4*)(w_ih + (size_t)grow * 4);
  const float bs = b_ih[grow] + b_hh[grow];
  const float4 efc = g_encfc[b * 64 + l];  // per-lane: w = l

  // ---- LDS init ----
  st_l[tid] = 0u;
  if (tid < 64) {
    c_l[tid] = 0.f;
    hn_l[tid] = 0.f;
    w2_l[tid] = w2[64 * p + tid];
    yh_l[tid] = ((const float4*)yhist)[b * 64 + tid];
  }
  if (tid < 16) fcy_l[tid] = fc_w[(tid >> 2) * 260 + 256 + (tid & 3)];
  if (tid < 4) fcb_l[tid] = fc_b[tid];
#pragma unroll
  for (int i = 0; i < 8; i++) {
    int idx = tid + 256 * i;  // 2048 uints
    int w = idx >> 5, u = idx & 31;
    ep_l[w * 33 + u] = g_ep16[(size_t)(b * 64 + w) * 128 + 32 * p + u];
  }
  __syncthreads();

  float a = 0.f;     // P1 own-part partial (zero state initially -> 0 is exact)
  float attw = 0.f;
  for (int t = 0; t < 64; t++) {
    // ---- fetch partner state quarters (posted end of step t-1) ----
    if (t > 0 && tid < 192) {
      const int j = tid >> 6;
      const int pq = (p + 1 + j) & 3;
      unsigned* f2 = &g_f2[b + 128 * pq];
      while ((int)ald_acq(f2) < t) __builtin_amdgcn_s_sleep(2);
      const int i = tid & 63;
      unsigned v = ald(&g_state[b + 128 * pq][i]);
      if (i < 32) st_l[32 * pq + i] = v;
      else st_l[128 + 32 * pq + (i - 32)] = v;
    }
    __syncthreads();  // B1: st_l full
    // ---- P1b: non-own 32-pair halves of this thread's k-quarter ----
#pragma unroll
    for (int half = 0; half < 2; half++) {
      if (half != ownHalf) {
        const uint4* hv = (const uint4*)&st_l[64 * kq + 32 * half];
#pragma unroll
        for (int i = 0; i < 8; i++) a = fd2x4u(w1r[8 * half + i], hv[i], a);
      }
    }
    a += __shfl_xor(a, 1, 64);
    a += __shfl_xor(a, 2, 64);
    if (kq == 0) hcp_l[row] = a;
    __syncthreads();  // B2: hcp ready
    // ---- P2: partial scores over own e-quarter (w=row, j=kq) ----
    {
      float s = 0.f;
      const unsigned* ep = &ep_l[row * 33 + 8 * kq];
#pragma unroll
      for (int i = 0; i < 8; i++) {
        h2 aa = __builtin_bit_cast(h2, ep[i]);
        int e0 = 16 * kq + 2 * i;
        s += w2_l[e0] * ftanh((float)aa.x + hcp_l[e0]);
        s += w2_l[e0 + 1] * ftanh((float)aa.y + hcp_l[e0 + 1]);
      }
      s += __shfl_xor(s, 1, 64);
      s += __shfl_xor(s, 2, 64);
      if (kq == 0) { att_l[row] = s; ast(&g_att[g][row], __builtin_bit_cast(unsigned, s)); }
    }
    __syncthreads();  // B3: att stores drained
    if (tid == 0) ast_rel(&g_f1[g], t + 1);
    // ---- gates h-part (independent of softmax; hides score-sync latency) ----
    float aA = bs;
    {
      const uint4* hv = (const uint4*)st_l;  // h pairs [0..128)
#pragma unroll
      for (int i = 0; i < 32; i++) aA = fd2x4u(whr[i], hv[i], aA);
    }
    // ---- combine scores + softmax + ytilde (per-wave redundant) ----
    {
      unsigned* fa = &g_f1[b + 128 * ((p + 1) & 3)];
      unsigned* fb = &g_f1[b + 128 * ((p + 2) & 3)];
      unsigned* fc = &g_f1[b + 128 * ((p + 3) & 3)];
      while ((int)ald_acq(fa) < t + 1) __builtin_amdgcn_s_sleep(2);
      while ((int)ald_acq(fb) < t + 1) __builtin_amdgcn_s_sleep(2);
      while ((int)ald_acq(fc) < t + 1) __builtin_amdgcn_s_sleep(2);
    }
    float sc = att_l[l] +
               __builtin_bit_cast(float, ald(&g_att[b + 128 * ((p + 1) & 3)][l])) +
               __builtin_bit_cast(float, ald(&g_att[b + 128 * ((p + 2) & 3)][l])) +
               __builtin_bit_cast(float, ald(&g_att[b + 128 * ((p + 3) & 3)][l]));
    float m = sc;
#pragma unroll
    for (int dd = 32; dd; dd >>= 1) m = fmaxf(m, __shfl_xor(m, dd, 64));
    float pr = __builtin_exp2f((sc - m) * 1.4426950408889634f);
    float su = pr;
#pragma unroll
    for (int dd = 32; dd; dd >>= 1) su += __shfl_xor(su, dd, 64);
    attw = pr * __builtin_amdgcn_rcpf(su);
    float4 yt4;
    {
      float rx = attw * efc.x, ry = attw * efc.y, rz = attw * efc.z, rw = attw * efc.w;
#pragma unroll
      for (int dd = 32; dd; dd >>= 1) {
        rx += __shfl_xor(rx, dd, 64);
        ry += __shfl_xor(ry, dd, 64);
        rz += __shfl_xor(rz, dd, 64);
        rw += __shfl_xor(rw, dd, 64);
      }
      float4 yv = yh_l[t];
      yt4.x = rx + fcb_l[0] + fcy_l[0] * yv.x + fcy_l[1] * yv.y + fcy_l[2] * yv.z + fcy_l[3] * yv.w;
      yt4.y = ry + fcb_l[1] + fcy_l[4] * yv.x + fcy_l[5] * yv.y + fcy_l[6] * yv.z + fcy_l[7] * yv.w;
      yt4.z = rz + fcb_l[2] + fcy_l[8] * yv.x + fcy_l[9] * yv.y + fcy_l[10] * yv.z + fcy_l[11] * yv.w;
      yt4.w = rw + fcb_l[3] + fcy_l[12] * yv.x + fcy_l[13] * yv.y + fcy_l[14] * yv.z + fcy_l[15] * yv.w;
    }
    aA += dot4(wih, yt4);
    ag_l[tid] = aA;
    __syncthreads();  // B4: gates ready
    // ---- LSTM elementwise, own d-quarter; post state ----
    if (tid < 32) {
      const int d0 = 2 * tid, d1 = d0 + 1;
      float i0 = fsigm(ag_l[d0]), i1 = fsigm(ag_l[d1]);
      float f0 = fsigm(ag_l[64 + d0]), f1 = fsigm(ag_l[64 + d1]);
      float G0 = ftanh(ag_l[128 + d0]), G1 = ftanh(ag_l[128 + d1]);
      float o0 = fsigm(ag_l[192 + d0]), o1 = fsigm(ag_l[192 + d1]);
      float cn0 = f0 * c_l[d0] + i0 * G0, cn1 = f1 * c_l[d1] + i1 * G1;
      float hn0 = o0 * ftanh(cn0), hn1 = o1 * ftanh(cn1);
      c_l[d0] = cn0; c_l[d1] = cn1;
      hn_l[d0] = hn0; hn_l[d1] = hn1;
      unsigned hp = pk(hn0, hn1), cp = pk(cn0, cn1);
      st_l[32 * p + tid] = hp;
      st_l[128 + 32 * p + tid] = cp;
      ast(&g_state[g][tid], hp);
      ast(&g_state[g][32 + tid], cp);
    }
    __syncthreads();  // B5: own state in LDS + global stores drained
    if (tid == 0) ast_rel(&g_f2[g], t + 1);
    // ---- P1a: own 32-pair half for next step (hides state-sync latency) ----
    a = 0.f;
    if (ownHalf >= 0) {
      const uint4* hv = (const uint4*)&st_l[64 * kq + 32 * ownHalf];
#pragma unroll
      for (int i = 0; i < 8; i++) a = fd2x4u(w1r[8 * ownHalf + i], hv[i], a);
    }
  }

  // ---- final: out[b,f] += fcf_h(own quarter)·h + [p==0] (attn·ENCFCF + fcf_b) ----
  {
    float v = fcf_w[q * 512 + 64 * p + l] * hn_l[l];
    if (p == 0) {
      float4 fv = g_encfcf[b * 64 + l];
      v += attw * ((const float*)&fv)[q];
    }
#pragma unroll
    for (int dd = 32; dd; dd >>= 1) v += __shfl_xor(v, dd, 64);
    if (l == 0) atomicAdd(out + b * 4 + q, v + ((p == 0) ? fcf_b[q] : 0.f));
  }
}

extern "C" void kernel_launch(void* const* d_in, const int* in_sizes, int n_in,
                              void* d_out, int out_size, void* d_ws, size_t ws_size,
                              hipStream_t stream) {
  (void)in_sizes; (void)n_in; (void)d_ws; (void)ws_size; (void)out_size;
  const float* enc   = (const float*)d_in[0];
  const float* yhist = (const float*)d_in[1];
  const float* w1    = (const float*)d_in[2];
  const float* b1    = (const float*)d_in[3];
  const float* w2    = (const float*)d_in[4];
  // d_in[5] = attn_b2: softmax-invariant -> unused
  const float* w_ih  = (const float*)d_in[6];
  const float* w_hh  = (const float*)d_in[7];
  const float* b_ih  = (const float*)d_in[8];
  const float* b_hh  = (const float*)d_in[9];
  const float* fc_w  = (const float*)d_in[10];
  const float* fc_b  = (const float*)d_in[11];
  const float* fcf_w = (const float*)d_in[12];
  const float* fcf_b = (const float*)d_in[13];
  float* out = (float*)d_out;

  reset_kernel<<<dim3(1), dim3(512), 0, stream>>>(out);
  eproj_kernel<<<dim3(512), dim3(256), 0, stream>>>(enc, w1, b1);
  encfc_kernel<<<dim3(512), dim3(256), 0, stream>>>(enc, fc_w, fcf_w);
  decoder_kernel<<<dim3(512), dim3(256), 0, stream>>>(w1, w_hh, yhist, w2, w_ih, b_ih,
                                                      b_hh, fc_w, fc_b, fcf_w, fcf_b, out);
}

// Round 6
// 6099.455 us; speedup vs baseline: 1.1297x; 1.1297x over previous
//
#include <hip/hip_runtime.h>

#define Bn 128
#define Wn 64

typedef _Float16 h2 __attribute__((ext_vector_type(2)));

// ---- inter-WG exchange state (flags reset every launch) ----
__device__ unsigned g_f1[512];               // score-partial ready, value = t+1
__device__ unsigned g_f2[512];               // state-quarter ready, value = t+1
__device__ unsigned g_att[512][64];          // score partials (f32 bits)
__device__ unsigned g_state[512][64];        // h pairs [0..32), c pairs [32..64)
__device__ unsigned g_ep16[Bn * Wn * 128];   // eproj f16 pairs [b][w][128]
__device__ float4 g_encfc[Bn * Wn];          // fc_w[:, :256] @ enc  per (b,w)
__device__ float4 g_encfcf[Bn * Wn];         // fcf_w[:, 256:] @ enc per (b,w)
// pre-packed f16 weight streams, laid out [p][i][tid] for coalesced reads
__device__ uint4 g_w1p[4 * 16 * 256];        // w1[h|c] quarter-shares   (256 KB)
__device__ uint4 g_whhp[4 * 32 * 256];       // w_hh quarter-shares      (512 KB)

__device__ __forceinline__ float ftanh(float x) {
  float p = __builtin_exp2f(x * 2.885390081777927f);
  return 1.0f - 2.0f * __builtin_amdgcn_rcpf(p + 1.0f);
}
__device__ __forceinline__ float fsigm(float x) {
  float p = __builtin_exp2f(-x * 1.4426950408889634f);
  return __builtin_amdgcn_rcpf(1.0f + p);
}
__device__ __forceinline__ float dot4(float4 a, float4 b) {
  return a.x * b.x + a.y * b.y + a.z * b.z + a.w * b.w;
}
__device__ __forceinline__ float fd2(unsigned w, unsigned h, float acc) {
  h2 a = __builtin_bit_cast(h2, w), b = __builtin_bit_cast(h2, h);
#if __has_builtin(__builtin_amdgcn_fdot2)
  return __builtin_amdgcn_fdot2(a, b, acc, false);
#else
  return acc + (float)a.x * (float)b.x + (float)a.y * (float)b.y;
#endif
}
__device__ __forceinline__ float fd2x4u(uint4 w, uint4 h, float acc) {
  acc = fd2(w.x, h.x, acc);
  acc = fd2(w.y, h.y, acc);
  acc = fd2(w.z, h.z, acc);
  acc = fd2(w.w, h.w, acc);
  return acc;
}
__device__ __forceinline__ unsigned pk(float a, float b) {
  h2 h = {(_Float16)a, (_Float16)b};
  return __builtin_bit_cast(unsigned, h);
}
__device__ __forceinline__ void ast(unsigned* p, unsigned v) {
  __hip_atomic_store(p, v, __ATOMIC_RELAXED, __HIP_MEMORY_SCOPE_AGENT);
}
__device__ __forceinline__ void ast_rel(unsigned* p, unsigned v) {
  __hip_atomic_store(p, v, __ATOMIC_RELEASE, __HIP_MEMORY_SCOPE_AGENT);
}
__device__ __forceinline__ unsigned ald(unsigned* p) {
  return __hip_atomic_load(p, __ATOMIC_RELAXED, __HIP_MEMORY_SCOPE_AGENT);
}
__device__ __forceinline__ unsigned ald_acq(unsigned* p) {
  return __hip_atomic_load(p, __ATOMIC_ACQUIRE, __HIP_MEMORY_SCOPE_AGENT);
}

// ---------------- reset: flags + out (atomicAdd target) ----------------
__global__ void reset_kernel(float* out) {
  int t = threadIdx.x;
  if (t < 512) { g_f1[t] = 0u; g_f2[t] = 0u; out[t] = 0.f; }
}

// ---------------- pack weights into [p][i][tid] coalesced f16 streams ----------------
__global__ __launch_bounds__(256) void pack_kernel(const float* __restrict__ w1,
                                                   const float* __restrict__ w_hh) {
  int idx = blockIdx.x * 256 + threadIdx.x;
  if (idx < 4 * 16 * 256) {
    int p = idx >> 12, i = (idx >> 8) & 15, tid = idx & 255;
    int row = 64 * p + (tid >> 2), kq = tid & 3;
    const float4* s = (const float4*)(w1 + (size_t)row * 768 + kq * 128 + 8 * i);
    float4 x = s[0], y = s[1];
    uint4 o;
    o.x = pk(x.x, x.y); o.y = pk(x.z, x.w);
    o.z = pk(y.x, y.y); o.w = pk(y.z, y.w);
    g_w1p[idx] = o;
  } else {
    int j = idx - 4 * 16 * 256;
    if (j >= 4 * 32 * 256) return;
    int p = j >> 13, i = (j >> 8) & 31, tid = j & 255;
    int q = tid >> 6, l = tid & 63;
    int grow = q * 256 + 64 * p + l;
    const float4* s = (const float4*)(w_hh + (size_t)grow * 256 + 8 * i);
    float4 x = s[0], y = s[1];
    uint4 o;
    o.x = pk(x.x, x.y); o.y = pk(x.z, x.w);
    o.z = pk(y.x, y.y); o.w = pk(y.z, y.w);
    g_whhp[j] = o;
  }
}

// ---------------- eproj: b1 + W1e @ enc -> f16 pairs ----------------
__global__ __launch_bounds__(256) void eproj_kernel(const float* __restrict__ enc,
                                                    const float* __restrict__ w1,
                                                    const float* __restrict__ b1) {
  __shared__ __align__(16) float4 encs[16][64];
  __shared__ float accs[16][256];
  const int m0 = blockIdx.x * 16;
  const int tid = threadIdx.x;
  const float4* eg = (const float4*)(enc + (size_t)m0 * 256);
#pragma unroll
  for (int i = 0; i < 4; i++) {
    int idx = tid + 256 * i;
    encs[idx >> 6][idx & 63] = eg[idx];
  }
  __syncthreads();
  const int e = tid;
  float acc[16];
#pragma unroll
  for (int i = 0; i < 16; i++) acc[i] = 0.f;
  const float4* wrow = (const float4*)(w1 + e * 768 + 512);
  for (int k4 = 0; k4 < 64; k4++) {
    float4 wv = wrow[k4];
#pragma unroll
    for (int i = 0; i < 16; i++) acc[i] += dot4(wv, encs[i][k4]);
  }
  float bb = b1[e];
#pragma unroll
  for (int i = 0; i < 16; i++) accs[i][e] = acc[i] + bb;
  __syncthreads();
#pragma unroll
  for (int r = 0; r < 8; r++) {
    int idx = r * 256 + tid;  // 0..2047
    int i = idx >> 7, jp = idx & 127;
    g_ep16[(size_t)(m0 + i) * 128 + jp] = pk(accs[i][2 * jp], accs[i][2 * jp + 1]);
  }
}

// ---------------- ENCFC / ENCFCF precompute ----------------
__global__ __launch_bounds__(256) void encfc_kernel(const float* __restrict__ enc,
                                                    const float* __restrict__ fc_w,
                                                    const float* __restrict__ fcf_w) {
  __shared__ __align__(16) float4 encs[16][64];
  const int m0 = blockIdx.x * 16;
  const int tid = threadIdx.x;
  const float4* eg = (const float4*)(enc + (size_t)m0 * 256);
#pragma unroll
  for (int i = 0; i < 4; i++) {
    int idx = tid + 256 * i;
    encs[idx >> 6][idx & 63] = eg[idx];
  }
  __syncthreads();
  if (tid < 128) {
    const int r = tid >> 3, o = tid & 7;
    const float* wr = (o < 4) ? (fc_w + o * 260) : (fcf_w + (o - 4) * 512 + 256);
    const float4* w4 = (const float4*)wr;
    float a = 0.f;
#pragma unroll 8
    for (int k = 0; k < 64; k++) a += dot4(w4[k], encs[r][k]);
    if (o < 4) ((float*)&g_encfc[m0 + r])[o] = a;
    else ((float*)&g_encfcf[m0 + r])[o - 4] = a;
  }
}

// ---------------- decoder: 4 WGs per chain; coalesced f16 weight stream ----------------
__global__ __launch_bounds__(256, 2) void decoder_kernel(
    const float* __restrict__ yhist, const float* __restrict__ w2,
    const float* __restrict__ w_ih, const float* __restrict__ b_ih,
    const float* __restrict__ b_hh,
    const float* __restrict__ fc_w, const float* __restrict__ fc_b,
    const float* __restrict__ fcf_w, const float* __restrict__ fcf_b,
    float* __restrict__ out) {
  __shared__ unsigned st_l[256];     // full state pairs: h [0..128), c [128..256)
  __shared__ float hcp_l[64];        // own e-quarter hcp
  __shared__ float att_l[64];
  __shared__ float ag_l[256];        // gates [q][d_local]
  __shared__ float c_l[64];          // own-quarter c (f32)
  __shared__ float hn_l[64];         // own-quarter h (f32)
  __shared__ float w2_l[64];
  __shared__ unsigned ep_l[64 * 33]; // eproj own e-quarter, stride 33
  __shared__ __align__(16) float4 yh_l[64];
  __shared__ float fcy_l[16];
  __shared__ float fcb_l[4];

  const int g = blockIdx.x, tid = threadIdx.x;
  const int b = g & 127, p = g >> 7;   // p in 0..3
  const int l = tid & 63, q = tid >> 6;

  // P1 mapping: 4 threads per e-row, each a 128-k quarter of the 512-k row
  const int row = tid >> 2, kq = tid & 3;
  // which 32-pair half of this thread's quarter is this WG's own state
  int ownHalf = -1;
  if (kq == (p >> 1) || kq == 2 + (p >> 1)) ownHalf = p & 1;

  // coalesced weight stream bases: element [i] at + 256*i
  const uint4* w1p = g_w1p + (p << 12) + tid;
  const uint4* whp = g_whhp + (p << 13) + tid;

  const int grow = q * 256 + 64 * p + l;  // gate row: wave q = gate (i,f,g,o)
  const float4 wih = *(const float4*)(w_ih + (size_t)grow * 4);
  const float bs = b_ih[grow] + b_hh[grow];
  const float4 efc = g_encfc[b * 64 + l];  // per-lane: w = l

  // ---- LDS init ----
  st_l[tid] = 0u;
  if (tid < 64) {
    c_l[tid] = 0.f;
    hn_l[tid] = 0.f;
    w2_l[tid] = w2[64 * p + tid];
    yh_l[tid] = ((const float4*)yhist)[b * 64 + tid];
  }
  if (tid < 16) fcy_l[tid] = fc_w[(tid >> 2) * 260 + 256 + (tid & 3)];
  if (tid < 4) fcb_l[tid] = fc_b[tid];
#pragma unroll
  for (int i = 0; i < 8; i++) {
    int idx = tid + 256 * i;  // 2048 uints
    int w = idx >> 5, u = idx & 31;
    ep_l[w * 33 + u] = g_ep16[(size_t)(b * 64 + w) * 128 + 32 * p + u];
  }
  __syncthreads();

  float a = 0.f;     // P1 own-part partial (zero state initially -> 0 is exact)
  float attw = 0.f;
  for (int t = 0; t < 64; t++) {
    // ---- fetch partner state quarters (posted end of step t-1) ----
    if (t > 0 && tid < 192) {
      const int j = tid >> 6;
      const int pq = (p + 1 + j) & 3;
      unsigned* f2 = &g_f2[b + 128 * pq];
      while ((int)ald_acq(f2) < t) __builtin_amdgcn_s_sleep(2);
      const int i = tid & 63;
      unsigned v = ald(&g_state[b + 128 * pq][i]);
      if (i < 32) st_l[32 * pq + i] = v;
      else st_l[128 + 32 * pq + (i - 32)] = v;
    }
    __syncthreads();  // B1: st_l full
    // ---- P1b: non-own 32-pair halves of this thread's k-quarter ----
#pragma unroll
    for (int half = 0; half < 2; half++) {
      if (half != ownHalf) {
        const uint4* hv = (const uint4*)&st_l[64 * kq + 32 * half];
#pragma unroll
        for (int i = 0; i < 8; i++) a = fd2x4u(w1p[(8 * half + i) * 256], hv[i], a);
      }
    }
    a += __shfl_xor(a, 1, 64);
    a += __shfl_xor(a, 2, 64);
    if (kq == 0) hcp_l[row] = a;
    __syncthreads();  // B2: hcp ready
    // ---- P2: partial scores over own e-quarter (w=row, j=kq) ----
    {
      float s = 0.f;
      const unsigned* ep = &ep_l[row * 33 + 8 * kq];
#pragma unroll
      for (int i = 0; i < 8; i++) {
        h2 aa = __builtin_bit_cast(h2, ep[i]);
        int e0 = 16 * kq + 2 * i;
        s += w2_l[e0] * ftanh((float)aa.x + hcp_l[e0]);
        s += w2_l[e0 + 1] * ftanh((float)aa.y + hcp_l[e0 + 1]);
      }
      s += __shfl_xor(s, 1, 64);
      s += __shfl_xor(s, 2, 64);
      if (kq == 0) { att_l[row] = s; ast(&g_att[g][row], __builtin_bit_cast(unsigned, s)); }
    }
    __syncthreads();  // B3: att stores drained
    if (tid == 0) ast_rel(&g_f1[g], t + 1);
    // ---- gates h-part (independent of softmax; hides score-sync latency) ----
    float aA = bs;
    {
      const uint4* hv = (const uint4*)st_l;  // h pairs [0..128)
#pragma unroll
      for (int i = 0; i < 32; i++) aA = fd2x4u(whp[i * 256], hv[i], aA);
    }
    // ---- combine scores + softmax + ytilde (per-wave redundant) ----
    {
      unsigned* fa = &g_f1[b + 128 * ((p + 1) & 3)];
      unsigned* fb = &g_f1[b + 128 * ((p + 2) & 3)];
      unsigned* fc = &g_f1[b + 128 * ((p + 3) & 3)];
      while ((int)ald_acq(fa) < t + 1) __builtin_amdgcn_s_sleep(2);
      while ((int)ald_acq(fb) < t + 1) __builtin_amdgcn_s_sleep(2);
      while ((int)ald_acq(fc) < t + 1) __builtin_amdgcn_s_sleep(2);
    }
    float sc = att_l[l] +
               __builtin_bit_cast(float, ald(&g_att[b + 128 * ((p + 1) & 3)][l])) +
               __builtin_bit_cast(float, ald(&g_att[b + 128 * ((p + 2) & 3)][l])) +
               __builtin_bit_cast(float, ald(&g_att[b + 128 * ((p + 3) & 3)][l]));
    float m = sc;
#pragma unroll
    for (int dd = 32; dd; dd >>= 1) m = fmaxf(m, __shfl_xor(m, dd, 64));
    float pr = __builtin_exp2f((sc - m) * 1.4426950408889634f);
    float su = pr;
#pragma unroll
    for (int dd = 32; dd; dd >>= 1) su += __shfl_xor(su, dd, 64);
    attw = pr * __builtin_amdgcn_rcpf(su);
    float4 yt4;
    {
      float rx = attw * efc.x, ry = attw * efc.y, rz = attw * efc.z, rw = attw * efc.w;
#pragma unroll
      for (int dd = 32; dd; dd >>= 1) {
        rx += __shfl_xor(rx, dd, 64);
        ry += __shfl_xor(ry, dd, 64);
        rz += __shfl_xor(rz, dd, 64);
        rw += __shfl_xor(rw, dd, 64);
      }
      float4 yv = yh_l[t];
      yt4.x = rx + fcb_l[0] + fcy_l[0] * yv.x + fcy_l[1] * yv.y + fcy_l[2] * yv.z + fcy_l[3] * yv.w;
      yt4.y = ry + fcb_l[1] + fcy_l[4] * yv.x + fcy_l[5] * yv.y + fcy_l[6] * yv.z + fcy_l[7] * yv.w;
      yt4.z = rz + fcb_l[2] + fcy_l[8] * yv.x + fcy_l[9] * yv.y + fcy_l[10] * yv.z + fcy_l[11] * yv.w;
      yt4.w = rw + fcb_l[3] + fcy_l[12] * yv.x + fcy_l[13] * yv.y + fcy_l[14] * yv.z + fcy_l[15] * yv.w;
    }
    aA += dot4(wih, yt4);
    ag_l[tid] = aA;
    __syncthreads();  // B4: gates ready
    // ---- LSTM elementwise, own d-quarter; post state ----
    if (tid < 32) {
      const int d0 = 2 * tid, d1 = d0 + 1;
      float i0 = fsigm(ag_l[d0]), i1 = fsigm(ag_l[d1]);
      float f0 = fsigm(ag_l[64 + d0]), f1 = fsigm(ag_l[64 + d1]);
      float G0 = ftanh(ag_l[128 + d0]), G1 = ftanh(ag_l[128 + d1]);
      float o0 = fsigm(ag_l[192 + d0]), o1 = fsigm(ag_l[192 + d1]);
      float cn0 = f0 * c_l[d0] + i0 * G0, cn1 = f1 * c_l[d1] + i1 * G1;
      float hn0 = o0 * ftanh(cn0), hn1 = o1 * ftanh(cn1);
      c_l[d0] = cn0; c_l[d1] = cn1;
      hn_l[d0] = hn0; hn_l[d1] = hn1;
      unsigned hp = pk(hn0, hn1), cp = pk(cn0, cn1);
      st_l[32 * p + tid] = hp;
      st_l[128 + 32 * p + tid] = cp;
      ast(&g_state[g][tid], hp);
      ast(&g_state[g][32 + tid], cp);
    }
    __syncthreads();  // B5: own state in LDS + global stores drained
    if (tid == 0) ast_rel(&g_f2[g], t + 1);
    // ---- P1a: own 32-pair half for next step (hides state-sync latency) ----
    a = 0.f;
    if (ownHalf >= 0) {
      const uint4* hv = (const uint4*)&st_l[64 * kq + 32 * ownHalf];
#pragma unroll
      for (int i = 0; i < 8; i++) a = fd2x4u(w1p[(8 * ownHalf + i) * 256], hv[i], a);
    }
  }

  // ---- final: out[b,f] += fcf_h(own quarter)·h + [p==0] (attn·ENCFCF + fcf_b) ----
  {
    float v = fcf_w[q * 512 + 64 * p + l] * hn_l[l];
    if (p == 0) {
      float4 fv = g_encfcf[b * 64 + l];
      v += attw * ((const float*)&fv)[q];
    }
#pragma unroll
    for (int dd = 32; dd; dd >>= 1) v += __shfl_xor(v, dd, 64);
    if (l == 0) atomicAdd(out + b * 4 + q, v + ((p == 0) ? fcf_b[q] : 0.f));
  }
}

extern "C" void kernel_launch(void* const* d_in, const int* in_sizes, int n_in,
                              void* d_out, int out_size, void* d_ws, size_t ws_size,
                              hipStream_t stream) {
  (void)in_sizes; (void)n_in; (void)d_ws; (void)ws_size; (void)out_size;
  const float* enc   = (const float*)d_in[0];
  const float* yhist = (const float*)d_in[1];
  const float* w1    = (const float*)d_in[2];
  const float* b1    = (const float*)d_in[3];
  const float* w2    = (const float*)d_in[4];
  // d_in[5] = attn_b2: softmax-invariant -> unused
  const float* w_ih  = (const float*)d_in[6];
  const float* w_hh  = (const float*)d_in[7];
  const float* b_ih  = (const float*)d_in[8];
  const float* b_hh  = (const float*)d_in[9];
  const float* fc_w  = (const float*)d_in[10];
  const float* fc_b  = (const float*)d_in[11];
  const float* fcf_w = (const float*)d_in[12];
  const float* fcf_b = (const float*)d_in[13];
  float* out = (float*)d_out;

  reset_kernel<<<dim3(1), dim3(512), 0, stream>>>(out);
  pack_kernel<<<dim3(192), dim3(256), 0, stream>>>(w1, w_hh);
  eproj_kernel<<<dim3(512), dim3(256), 0, stream>>>(enc, w1, b1);
  encfc_kernel<<<dim3(512), dim3(256), 0, stream>>>(enc, fc_w, fcf_w);
  decoder_kernel<<<dim3(512), dim3(256), 0, stream>>>(yhist, w2, w_ih, b_ih, b_hh,
                                                      fc_w, fc_b, fcf_w, fcf_b, out);
}

// Round 7
// 708.491 us; speedup vs baseline: 9.7260x; 8.6091x over previous
//
#include <hip/hip_runtime.h>

#define Bn 128
#define Wn 64

typedef _Float16 h2 __attribute__((ext_vector_type(2)));

// ---- inter-WG exchange state (flags reset every launch) ----
__device__ unsigned g_f2[256];                 // state-half ready, value = t+1
__device__ unsigned g_state2[256][2][128];     // [g][t&1][h pairs 0..64 | c pairs 64..128)
__device__ unsigned g_ep16[Bn * Wn * 128];     // eproj f16 pairs [b][w][128]
__device__ float4 g_encfc[Bn * Wn];            // fc_w[:, :256] @ enc  per (b,w)
__device__ float4 g_encfcf[Bn * Wn];           // fcf_w[:, 256:] @ enc per (b,w)
// pre-packed coalesced f16 streams, element [i] at +512*i, lane-consecutive tid
__device__ uint4 g_w1q[32 * 512];              // full w1[h|c] (256 KB), [i][tid]
__device__ uint4 g_whq[2 * 32 * 512];          // w_hh d-halves (512 KB), [p][i][tid]

__device__ __forceinline__ float ftanh(float x) {
  float p = __builtin_exp2f(x * 2.885390081777927f);
  return 1.0f - 2.0f * __builtin_amdgcn_rcpf(p + 1.0f);
}
__device__ __forceinline__ float fsigm(float x) {
  float p = __builtin_exp2f(-x * 1.4426950408889634f);
  return __builtin_amdgcn_rcpf(1.0f + p);
}
__device__ __forceinline__ float dot4(float4 a, float4 b) {
  return a.x * b.x + a.y * b.y + a.z * b.z + a.w * b.w;
}
__device__ __forceinline__ float fd2(unsigned w, unsigned h, float acc) {
  h2 a = __builtin_bit_cast(h2, w), b = __builtin_bit_cast(h2, h);
#if __has_builtin(__builtin_amdgcn_fdot2)
  return __builtin_amdgcn_fdot2(a, b, acc, false);
#else
  return acc + (float)a.x * (float)b.x + (float)a.y * (float)b.y;
#endif
}
__device__ __forceinline__ float fd2x4u(uint4 w, uint4 h, float acc) {
  acc = fd2(w.x, h.x, acc);
  acc = fd2(w.y, h.y, acc);
  acc = fd2(w.z, h.z, acc);
  acc = fd2(w.w, h.w, acc);
  return acc;
}
__device__ __forceinline__ unsigned pk(float a, float b) {
  h2 h = {(_Float16)a, (_Float16)b};
  return __builtin_bit_cast(unsigned, h);
}
__device__ __forceinline__ void ast(unsigned* p, unsigned v) {
  __hip_atomic_store(p, v, __ATOMIC_RELAXED, __HIP_MEMORY_SCOPE_AGENT);
}
__device__ __forceinline__ unsigned ald(unsigned* p) {
  return __hip_atomic_load(p, __ATOMIC_RELAXED, __HIP_MEMORY_SCOPE_AGENT);
}

// ---------------- reset: flags + out (atomicAdd target) ----------------
__global__ void reset_kernel(float* out) {
  int t = threadIdx.x;
  if (t < 256) g_f2[t] = 0u;
  if (t < 512) out[t] = 0.f;
}

// ---------------- pack weights into [i][tid] coalesced f16 quad streams ----------------
__global__ __launch_bounds__(256) void pack_kernel(const float* __restrict__ w1,
                                                   const float* __restrict__ w_hh) {
  int idx = blockIdx.x * 256 + threadIdx.x;  // 49152 tasks
  const float* src;
  uint4* dst;
  if (idx < 32 * 512) {
    int i = idx >> 9, t = idx & 511;
    int e = t >> 1, kh = t & 1;
    int col = (i < 16) ? (kh * 128 + 8 * i) : (256 + kh * 128 + 8 * (i - 16));
    src = w1 + (size_t)e * 768 + col;
    dst = g_w1q + idx;
  } else {
    int j = idx - 32 * 512;
    int p = j >> 14, rem = j & 16383, i = rem >> 9, t = rem & 511;
    int q = t >> 7, dl = t & 127;
    int row = q * 256 + 128 * p + dl;
    src = w_hh + (size_t)row * 256 + 8 * i;
    dst = g_whq + j;
  }
  uint4 o;
  o.x = pk(src[0], src[1]); o.y = pk(src[2], src[3]);
  o.z = pk(src[4], src[5]); o.w = pk(src[6], src[7]);
  *dst = o;
}

// ---------------- eproj: b1 + W1e @ enc -> f16 pairs ----------------
__global__ __launch_bounds__(256) void eproj_kernel(const float* __restrict__ enc,
                                                    const float* __restrict__ w1,
                                                    const float* __restrict__ b1) {
  __shared__ __align__(16) float4 encs[16][64];
  __shared__ float accs[16][256];
  const int m0 = blockIdx.x * 16;
  const int tid = threadIdx.x;
  const float4* eg = (const float4*)(enc + (size_t)m0 * 256);
#pragma unroll
  for (int i = 0; i < 4; i++) {
    int idx = tid + 256 * i;
    encs[idx >> 6][idx & 63] = eg[idx];
  }
  __syncthreads();
  const int e = tid;
  float acc[16];
#pragma unroll
  for (int i = 0; i < 16; i++) acc[i] = 0.f;
  const float4* wrow = (const float4*)(w1 + e * 768 + 512);
  for (int k4 = 0; k4 < 64; k4++) {
    float4 wv = wrow[k4];
#pragma unroll
    for (int i = 0; i < 16; i++) acc[i] += dot4(wv, encs[i][k4]);
  }
  float bb = b1[e];
#pragma unroll
  for (int i = 0; i < 16; i++) accs[i][e] = acc[i] + bb;
  __syncthreads();
#pragma unroll
  for (int r = 0; r < 8; r++) {
    int idx = r * 256 + tid;
    int i = idx >> 7, jp = idx & 127;
    g_ep16[(size_t)(m0 + i) * 128 + jp] = pk(accs[i][2 * jp], accs[i][2 * jp + 1]);
  }
}

// ---------------- ENCFC / ENCFCF precompute ----------------
__global__ __launch_bounds__(256) void encfc_kernel(const float* __restrict__ enc,
                                                    const float* __restrict__ fc_w,
                                                    const float* __restrict__ fcf_w) {
  __shared__ __align__(16) float4 encs[16][64];
  const int m0 = blockIdx.x * 16;
  const int tid = threadIdx.x;
  const float4* eg = (const float4*)(enc + (size_t)m0 * 256);
#pragma unroll
  for (int i = 0; i < 4; i++) {
    int idx = tid + 256 * i;
    encs[idx >> 6][idx & 63] = eg[idx];
  }
  __syncthreads();
  if (tid < 128) {
    const int r = tid >> 3, o = tid & 7;
    const float* wr = (o < 4) ? (fc_w + o * 260) : (fcf_w + (o - 4) * 512 + 256);
    const float4* w4 = (const float4*)wr;
    float a = 0.f;
#pragma unroll 8
    for (int k = 0; k < 64; k++) a += dot4(w4[k], encs[r][k]);
    if (o < 4) ((float*)&g_encfc[m0 + r])[o] = a;
    else ((float*)&g_encfcf[m0 + r])[o - 4] = a;
  }
}

// ---------------- decoder: 2 WGs/chain, ONE sync/step, coalesced L2 streams ----------------
__global__ __launch_bounds__(512) void decoder_kernel(
    const float* __restrict__ yhist, const float* __restrict__ w2,
    const float* __restrict__ w_ih, const float* __restrict__ b_ih,
    const float* __restrict__ b_hh,
    const float* __restrict__ fc_w, const float* __restrict__ fc_b,
    const float* __restrict__ fcf_w, const float* __restrict__ fcf_b,
    float* __restrict__ out) {
  __shared__ __align__(16) unsigned st_l[256];  // h pairs [0..128) | c pairs [128..256)
  __shared__ float hcp_l[256];
  __shared__ float att_l[64];
  __shared__ float ag_l[512];                   // gates [q][dl], q=i,f,g,o
  __shared__ float w2_l[256];
  __shared__ unsigned ep_l[64 * 132];           // eproj [w][pair], stride 132
  __shared__ __align__(16) float4 yh_l[64];
  __shared__ float fcy_l[16];
  __shared__ float fcb_l[4];

  const int g = blockIdx.x, tid = threadIdx.x;
  const int b = g & 127, p = g >> 7, other = g ^ 128;
  const int l = tid & 63, wv = tid >> 6;

  const int kh = tid & 1, e_own = tid >> 1;
  const int q = tid >> 7, dl = tid & 127;
  const int grow = q * 256 + 128 * p + dl;
  const float4 wih = *(const float4*)(w_ih + (size_t)grow * 4);
  const float bs = b_ih[grow] + b_hh[grow];
  const float4 efc = g_encfc[b * 64 + l];

  const uint4* w1base = g_w1q + tid;
  const uint4* whbase = g_whq + (p << 14) + tid;

  if (tid < 256) { st_l[tid] = 0u; w2_l[tid] = w2[tid]; }
  if (tid < 64) yh_l[tid] = ((const float4*)yhist)[b * 64 + tid];
  if (tid < 16) fcy_l[tid] = fc_w[(tid >> 2) * 260 + 256 + (tid & 3)];
  if (tid < 4) fcb_l[tid] = fc_b[tid];
#pragma unroll
  for (int i = 0; i < 16; i++) {
    int idx = tid + 512 * i;  // 8192 payload uints
    int w = idx >> 7, u = idx & 127;
    ep_l[w * 132 + u] = g_ep16[(size_t)(b * 64 + w) * 128 + u];
  }
  float c0 = 0.f, c1 = 0.f;
  __syncthreads();

  float attw = 0.f;
  const uint4* stq = (const uint4*)st_l;
  for (int t = 0; t < Wn; t++) {
    // ---- P1: hcp[e_own] over k-half (full w1 stream) ----
    {
      float a = 0.f;
#pragma unroll
      for (int i = 0; i < 16; i++) a = fd2x4u(w1base[i * 512], stq[kh * 16 + i], a);
#pragma unroll
      for (int i = 0; i < 16; i++) a = fd2x4u(w1base[(16 + i) * 512], stq[32 + kh * 16 + i], a);
      a += __shfl_xor(a, 1, 64);
      if (kh == 0) hcp_l[e_own] = a;
    }
    __syncthreads();  // B1
    // ---- P2: full scores ----
    {
      const int w = tid >> 3, j = tid & 7;
      const unsigned* ep = &ep_l[w * 132 + j * 16];
      const float* hp = &hcp_l[32 * j];
      const float* vv = &w2_l[32 * j];
      float s = 0.f;
#pragma unroll
      for (int i = 0; i < 4; i++) {
        uint4 u = *(const uint4*)(ep + 4 * i);
        float4 h0 = *(const float4*)(hp + 8 * i);
        float4 h1 = *(const float4*)(hp + 8 * i + 4);
        float4 v0 = *(const float4*)(vv + 8 * i);
        float4 v1 = *(const float4*)(vv + 8 * i + 4);
        h2 aa;
        aa = __builtin_bit_cast(h2, u.x);
        s += v0.x * ftanh((float)aa.x + h0.x) + v0.y * ftanh((float)aa.y + h0.y);
        aa = __builtin_bit_cast(h2, u.y);
        s += v0.z * ftanh((float)aa.x + h0.z) + v0.w * ftanh((float)aa.y + h0.w);
        aa = __builtin_bit_cast(h2, u.z);
        s += v1.x * ftanh((float)aa.x + h1.x) + v1.y * ftanh((float)aa.y + h1.y);
        aa = __builtin_bit_cast(h2, u.w);
        s += v1.z * ftanh((float)aa.x + h1.z) + v1.w * ftanh((float)aa.y + h1.w);
      }
      s += __shfl_xor(s, 1, 64);
      s += __shfl_xor(s, 2, 64);
      s += __shfl_xor(s, 4, 64);
      if (j == 0) att_l[w] = s;
    }
    __syncthreads();  // B2
    // ---- softmax + ytilde (per-wave redundant) ----
    {
      float sc = att_l[l];
      float m = sc;
#pragma unroll
      for (int dd = 32; dd; dd >>= 1) m = fmaxf(m, __shfl_xor(m, dd, 64));
      float pr = __builtin_exp2f((sc - m) * 1.4426950408889634f);
      float su = pr;
#pragma unroll
      for (int dd = 32; dd; dd >>= 1) su += __shfl_xor(su, dd, 64);
      attw = pr * __builtin_amdgcn_rcpf(su);
    }
    float4 yt4;
    {
      float rx = attw * efc.x, ry = attw * efc.y, rz = attw * efc.z, rw = attw * efc.w;
#pragma unroll
      for (int dd = 32; dd; dd >>= 1) {
        rx += __shfl_xor(rx, dd, 64);
        ry += __shfl_xor(ry, dd, 64);
        rz += __shfl_xor(rz, dd, 64);
        rw += __shfl_xor(rw, dd, 64);
      }
      float4 yv = yh_l[t];
      yt4.x = rx + fcb_l[0] + fcy_l[0] * yv.x + fcy_l[1] * yv.y + fcy_l[2] * yv.z + fcy_l[3] * yv.w;
      yt4.y = ry + fcb_l[1] + fcy_l[4] * yv.x + fcy_l[5] * yv.y + fcy_l[6] * yv.z + fcy_l[7] * yv.w;
      yt4.z = rz + fcb_l[2] + fcy_l[8] * yv.x + fcy_l[9] * yv.y + fcy_l[10] * yv.z + fcy_l[11] * yv.w;
      yt4.w = rw + fcb_l[3] + fcy_l[12] * yv.x + fcy_l[13] * yv.y + fcy_l[14] * yv.z + fcy_l[15] * yv.w;
    }
    // ---- gates: one row/thread over own d-half ----
    {
      float aA = bs + dot4(wih, yt4);
#pragma unroll
      for (int i = 0; i < 32; i++) aA = fd2x4u(whbase[i * 512], stq[i], aA);
      ag_l[q * 128 + dl] = aA;
    }
    __syncthreads();  // B3
    // ---- elementwise (wave 0) || fetch partner state (wave 4) ----
    if (wv == 0) {
      const int d0 = 2 * l, d1 = d0 + 1;
      float i0 = fsigm(ag_l[d0]), i1 = fsigm(ag_l[d1]);
      float f0 = fsigm(ag_l[128 + d0]), f1 = fsigm(ag_l[128 + d1]);
      float G0 = ftanh(ag_l[256 + d0]), G1 = ftanh(ag_l[256 + d1]);
      float o0 = fsigm(ag_l[384 + d0]), o1 = fsigm(ag_l[384 + d1]);
      float cn0 = f0 * c0 + i0 * G0, cn1 = f1 * c1 + i1 * G1;
      float hn0 = o0 * ftanh(cn0), hn1 = o1 * ftanh(cn1);
      c0 = cn0; c1 = cn1;
      unsigned hp = pk(hn0, hn1), cp = pk(cn0, cn1);
      st_l[64 * p + l] = hp;
      st_l[128 + 64 * p + l] = cp;
      if (t < 63) {
        ast(&g_state2[g][t & 1][l], hp);
        ast(&g_state2[g][t & 1][64 + l], cp);
        asm volatile("s_waitcnt vmcnt(0)" ::: "memory");
        if (l == 0) ast(&g_f2[g], (unsigned)(t + 1));
      }
    } else if (wv == 4 && t < 63) {
      while ((int)ald(&g_f2[other]) < t + 1) __builtin_amdgcn_s_sleep(4);
      asm volatile("" ::: "memory");
      unsigned hp = ald(&g_state2[other][t & 1][l]);
      unsigned cp = ald(&g_state2[other][t & 1][64 + l]);
      st_l[64 * (1 - p) + l] = hp;
      st_l[128 + 64 * (1 - p) + l] = cp;
    }
    __syncthreads();  // B4
  }

  // ---- final: out[b,f] += fcf_h(own d-half)·h + [p==0](attn·ENCFCF + fcf_b) ----
  if (wv < 4) {
    const int f = wv;
    h2 hh = __builtin_bit_cast(h2, st_l[64 * p + l]);
    float v = fcf_w[f * 512 + 128 * p + 2 * l] * (float)hh.x +
              fcf_w[f * 512 + 128 * p + 2 * l + 1] * (float)hh.y;
    if (p == 0) {
      float4 fv = g_encfcf[b * 64 + l];
      v += attw * ((const float*)&fv)[f];
    }
#pragma unroll
    for (int dd = 32; dd; dd >>= 1) v += __shfl_xor(v, dd, 64);
    if (l == 0) atomicAdd(out + b * 4 + f, v + ((p == 0) ? fcf_b[f] : 0.f));
  }
}

extern "C" void kernel_launch(void* const* d_in, const int* in_sizes, int n_in,
                              void* d_out, int out_size, void* d_ws, size_t ws_size,
                              hipStream_t stream) {
  (void)in_sizes; (void)n_in; (void)d_ws; (void)ws_size; (void)out_size;
  const float* enc   = (const float*)d_in[0];
  const float* yhist = (const float*)d_in[1];
  const float* w1    = (const float*)d_in[2];
  const float* b1    = (const float*)d_in[3];
  const float* w2    = (const float*)d_in[4];
  // d_in[5] = attn_b2: softmax-invariant -> unused
  const float* w_ih  = (const float*)d_in[6];
  const float* w_hh  = (const float*)d_in[7];
  const float* b_ih  = (const float*)d_in[8];
  const float* b_hh  = (const float*)d_in[9];
  const float* fc_w  = (const float*)d_in[10];
  const float* fc_b  = (const float*)d_in[11];
  const float* fcf_w = (const float*)d_in[12];
  const float* fcf_b = (const float*)d_in[13];
  float* out = (float*)d_out;

  reset_kernel<<<dim3(1), dim3(512), 0, stream>>>(out);
  pack_kernel<<<dim3(192), dim3(256), 0, stream>>>(w1, w_hh);
  eproj_kernel<<<dim3(512), dim3(256), 0, stream>>>(enc, w1, b1);
  encfc_kernel<<<dim3(512), dim3(256), 0, stream>>>(enc, fc_w, fcf_w);
  decoder_kernel<<<dim3(256), dim3(512), 0, stream>>>(yhist, w2, w_ih, b_ih, b_hh,
                                                      fc_w, fc_b, fcf_w, fcf_b, out);
}